// Round 1
// baseline (81.718 us; speedup 1.0000x reference)
//
#include <hip/hip_runtime.h>

// Zero-insertion 2x upsample (PadWithin2D), stride=2.
// in:  (B=16, C=64, H=128, W=128) float32
// out: (B,C,2H,2W) float32; out[..., ::2, ::2] = in, zeros elsewhere.
//
// Mapping: each float4 of the output is one "t". Output row = 256 floats
// = 64 float4s, so row = t>>6, slot q = t&63. A wave (64 lanes, t
// consecutive, base 64-aligned) covers exactly one output row:
//  - odd  oh: pure-zero float4 store (write-only stream)
//  - even oh: read float2 in[row_base + 2q] -> store {x,0,y,0}
// Reads: 64 lanes x 8B = 512B contiguous. Writes: 64 x 16B = 1KiB contiguous.

__global__ __launch_bounds__(256) void PadWithin2D_kernel(
    const float* __restrict__ in, float* __restrict__ out, long long total_vec4) {
    const long long stride = (long long)gridDim.x * blockDim.x;
    for (long long t = (long long)blockIdx.x * blockDim.x + threadIdx.x;
         t < total_vec4; t += stride) {
        const int row = (int)(t >> 6);   // combined (b*C+c)*256 + oh
        const int q   = (int)(t & 63);   // float4 slot within the 256-wide row
        const int oh  = row & 255;
        float4 v4;
        if (oh & 1) {
            v4 = make_float4(0.f, 0.f, 0.f, 0.f);
        } else {
            const int bc = row >> 8;     // b*C + c
            const int ih = oh >> 1;
            const float2* inrow =
                (const float2*)(in + ((long long)bc * 128 + ih) * 128);
            const float2 v = inrow[q];   // input elements 2q, 2q+1
            v4 = make_float4(v.x, 0.f, v.y, 0.f);
        }
        ((float4*)out)[t] = v4;
    }
}

extern "C" void kernel_launch(void* const* d_in, const int* in_sizes, int n_in,
                              void* d_out, int out_size, void* d_ws, size_t ws_size,
                              hipStream_t stream) {
    const float* in = (const float*)d_in[0];
    float* out = (float*)d_out;
    // out_size = 16*64*256*256 = 67,108,864 floats -> 16,777,216 float4s
    const long long total_vec4 = (long long)out_size / 4;
    const int block = 256;
    int grid = 2048;  // grid-stride; 256 CUs x 8 blocks
    PadWithin2D_kernel<<<grid, block, 0, stream>>>(in, out, total_vec4);
}

// Round 3
// 53.672 us; speedup vs baseline: 1.5226x; 1.5226x over previous
//
#include <hip/hip_runtime.h>

// Zero-insertion 2x upsample (PadWithin2D), stride=2.
// in:  (B=16, C=64, H=128, W=128) float32  (= 8,388,608 float2)
// out: (B,C,256,256) float32; out[..., ::2, ::2] = in, zeros elsewhere.
//
// Branchless input-driven mapping: thread t owns input float2 #t
// (row r = t>>6, slot q = t&63). It writes:
//   even output row 2*ih, float4 slot q:   {x, 0, y, 0}
//   odd  output row 2*ih+1, float4 slot q: {0, 0, 0, 0}
// Output float4 index algebra: o = 2*t - q  (and o+64 for the odd row).
// Per wave: 512 B contiguous read, 2x 1 KiB contiguous writes. No branch,
// so the unrolled loop issues all loads before the dependent stores.
// Native ext_vector float4 (HIP_vector_type is rejected by the
// nontemporal builtin).

typedef float vf4 __attribute__((ext_vector_type(4)));
typedef float vf2 __attribute__((ext_vector_type(2)));

__global__ __launch_bounds__(256) void PadWithin2D_kernel(
    const vf2* __restrict__ in, vf4* __restrict__ out,
    int total, int iters) {
    const int nth = gridDim.x * blockDim.x;
    const int tid = blockIdx.x * blockDim.x + threadIdx.x;
    const vf4 zero = (vf4){0.f, 0.f, 0.f, 0.f};
    #pragma unroll 4
    for (int k = 0; k < iters; ++k) {
        const int t = tid + k * nth;
        const int q = t & 63;
        const vf2 v = in[t];
        const long long o = 2ll * t - q;
        vf4 ev = (vf4){v.x, 0.f, v.y, 0.f};
        __builtin_nontemporal_store(ev, &out[o]);
        __builtin_nontemporal_store(zero, &out[o + 64]);
    }
    // tail (not taken for the benched shape: 8,388,608 % 1,048,576 == 0)
    const int t = tid + iters * nth;
    if (t < total) {
        const int q = t & 63;
        const vf2 v = in[t];
        const long long o = 2ll * t - q;
        vf4 ev = (vf4){v.x, 0.f, v.y, 0.f};
        __builtin_nontemporal_store(ev, &out[o]);
        __builtin_nontemporal_store(zero, &out[o + 64]);
    }
}

extern "C" void kernel_launch(void* const* d_in, const int* in_sizes, int n_in,
                              void* d_out, int out_size, void* d_ws, size_t ws_size,
                              hipStream_t stream) {
    const vf2* in = (const vf2*)d_in[0];
    vf4* out = (vf4*)d_out;
    const int total = out_size / 8;      // input float2 count = 8,388,608
    const int block = 256;
    const int grid = 4096;               // 1,048,576 threads -> 8 exact iters
    const int nth = grid * block;
    const int iters = total / nth;       // exact-trip main loop, tail guarded
    PadWithin2D_kernel<<<grid, block, 0, stream>>>(in, out, total, iters);
}